// Round 2
// baseline (1815.681 us; speedup 1.0000x reference)
//
#include <hip/hip_runtime.h>
#include <hip/hip_bf16.h>
#include <math.h>

typedef __hip_bfloat16 bf16;
typedef unsigned short u16;
typedef __attribute__((ext_vector_type(8))) short short8;
typedef __attribute__((ext_vector_type(8))) unsigned short ushort8;
typedef __attribute__((ext_vector_type(4))) float f32x4;

#define PP 1024
#define LL 32
#define EE 512
#define DD 768
#define NLAYER 6
#define FFDIM 3072

__device__ __forceinline__ float bf2f(u16 u) { return __uint_as_float(((unsigned)u) << 16); }
// fp32 -> bf16 (RNE), finite inputs only
__device__ __forceinline__ u16 f2b(float x) {
  unsigned u = __float_as_uint(x);
  return (u16)((u + 0x7FFFu + ((u >> 16) & 1u)) >> 16);
}

// ---------------------------------------------------------------------------
// emb[pl][:] = (l < len[p]) ? byte_emb[tok] + local_pos[l] : 0   (fp32 in, bf16 out)
// pl is chunk-local; tokens/lengths pointers pre-offset by caller.
// ---------------------------------------------------------------------------
__global__ __launch_bounds__(256) void embed_kernel(
    const int* __restrict__ tokens, const int* __restrict__ lengths,
    const float* __restrict__ byte_emb, const float* __restrict__ local_pos,
    bf16* __restrict__ emb)
{
  int pl = blockIdx.x;
  int p = pl >> 5, l = pl & 31;
  bool valid = l < lengths[p];
  int tok = tokens[pl];
  const float* be = byte_emb + (long)tok * EE;
  const float* lp = local_pos + (long)l * EE;
  u16* out = (u16*)emb + (long)pl * EE;
  for (int e = threadIdx.x; e < EE; e += 256) {
    float v = valid ? be[e] + lp[e] : 0.f;
    out[e] = f2b(v);
  }
}

// ---------------------------------------------------------------------------
// C = A @ B^T (+bias)(+addf)(gelu). A: bf16 [M,K] (lda). B: [N,K] (ldb),
// bf16 or fp32 per template (converted to bf16 in staging). fp32 accum.
// 64x64 tile / 256 threads, mfma_f32_16x16x32_bf16. M%64==0, K%32==0; N guarded.
// Batched via blockIdx.z with sAb/sBb/sCb element strides; bias[bz*biasStride+c].
// ---------------------------------------------------------------------------
template<bool BF32>
__global__ __launch_bounds__(256) void gemm_bt(
    const bf16* A, long sAb, int lda,
    const void* Bv, long sBb, int ldb,
    float* Cf, bf16* Cb, long sCb, int ldc,
    const float* bias, int biasStride,
    const float* addf,
    int M, int N, int K, int act)
{
  __shared__ u16 As[64][40];   // row stride 80 B (16B-aligned), padded
  __shared__ u16 Bs[64][40];
  int bz = blockIdx.z;
  const u16* Ap = (const u16*)A + (long)bz * sAb;
  long coff = (long)bz * sCb;
  int m0 = blockIdx.y * 64, n0 = blockIdx.x * 64;
  int tid = threadIdx.x;
  int wave = tid >> 6, lane = tid & 63;
  int lr = tid >> 2;          // staging row 0..63
  int lc = (tid & 3) << 3;    // staging col (elements)
  f32x4 acc[4] = {{0.f,0.f,0.f,0.f},{0.f,0.f,0.f,0.f},{0.f,0.f,0.f,0.f},{0.f,0.f,0.f,0.f}};
  int arow = (wave << 4) + (lane & 15);
  int kfrag = (lane >> 4) << 3;
  for (int k0 = 0; k0 < K; k0 += 32) {
    uint4 av = *(const uint4*)(Ap + (long)(m0 + lr) * lda + k0 + lc);
    ushort8 bv8 = {0,0,0,0,0,0,0,0};
    int brow = n0 + lr;
    if (brow < N) {
      if (BF32) {
        const float* bp = (const float*)Bv + (long)bz * sBb + (long)brow * ldb + k0 + lc;
        float4 x0 = *(const float4*)bp;
        float4 x1 = *(const float4*)(bp + 4);
        bv8[0] = f2b(x0.x); bv8[1] = f2b(x0.y); bv8[2] = f2b(x0.z); bv8[3] = f2b(x0.w);
        bv8[4] = f2b(x1.x); bv8[5] = f2b(x1.y); bv8[6] = f2b(x1.z); bv8[7] = f2b(x1.w);
      } else {
        const u16* bp = (const u16*)Bv + (long)bz * sBb + (long)brow * ldb + k0 + lc;
        bv8 = *(const ushort8*)bp;
      }
    }
    *(uint4*)&As[lr][lc] = av;
    *(ushort8*)&Bs[lr][lc] = bv8;
    __syncthreads();
    short8 af = *(const short8*)&As[arow][kfrag];
#pragma unroll
    for (int nt = 0; nt < 4; nt++) {
      short8 bfr = *(const short8*)&Bs[(nt << 4) + (lane & 15)][kfrag];
      acc[nt] = __builtin_amdgcn_mfma_f32_16x16x32_bf16(af, bfr, acc[nt], 0, 0, 0);
    }
    __syncthreads();
  }
  int rbase = m0 + (wave << 4) + ((lane >> 4) << 2);
#pragma unroll
  for (int nt = 0; nt < 4; nt++) {
    int c = n0 + (nt << 4) + (lane & 15);
    if (c >= N) continue;
    float bvl = bias ? bias[bz * biasStride + c] : 0.f;
#pragma unroll
    for (int j = 0; j < 4; j++) {
      int r = rbase + j;
      long idx = coff + (long)r * ldc + c;
      float v = acc[nt][j] + bvl;
      if (addf) v += addf[idx];
      if (act == 1) v = 0.5f * v * (1.f + erff(v * 0.70710678118654752f));
      if (Cf) Cf[idx] = v;
      if (Cb) Cb[idx] = __float2bfloat16(v);
    }
  }
}

// ---------------------------------------------------------------------------
// Per-patch MHA over 32 bytes (4 heads, d=128) fused with the masked mean,
// with the V path commuted: z_h = wsum_h @ emb (emb recomputed from fp32
// tables). qk: chunk-local [npat][32][1024] bf16 (Q | K). Z: [P][4][512] bf16.
// One 256-thread block per patch. tokens/lengths/Z pre-offset by caller.
// ---------------------------------------------------------------------------
__global__ __launch_bounds__(256) void patch_attn(
    const bf16* __restrict__ qk,
    const int* __restrict__ tokens, const int* __restrict__ lengths,
    const float* __restrict__ byte_emb, const float* __restrict__ local_pos,
    bf16* __restrict__ Z)
{
  __shared__ u16 ks[32][512];     // 32 KB: K rows for all 4 heads
  __shared__ float sc[4][32][32]; // 16 KB scores
  __shared__ float wsum[4][32];
  __shared__ int tok_s[32];
  __shared__ int cnt_s;
  int pl = blockIdx.x;
  int tid = threadIdx.x;
  if (tid < 32) tok_s[tid] = tokens[pl * 32 + tid];
  if (tid == 0) cnt_s = lengths[pl];
  const u16* base = (const u16*)qk + (long)pl * 32 * 1024;
  for (int idx = tid; idx < 2048; idx += 256) {   // stage K: 32 rows x 64 vec8
    int r = idx >> 6, c = (idx & 63) << 3;
    *(uint4*)&ks[r][c] = *(const uint4*)(base + r * 1024 + 512 + c);
  }
  int h = tid >> 6, lane = tid & 63;   // wave == head
  int qi = lane >> 1;
  int j0 = (lane & 1) << 4;
  ushort8 qreg[16];
  const u16* qp = base + qi * 1024 + h * 128;
#pragma unroll
  for (int c = 0; c < 16; c++) qreg[c] = *(const ushort8*)(qp + (c << 3));
  __syncthreads();
  int cnt = cnt_s;
  float accs[16];
#pragma unroll
  for (int jj = 0; jj < 16; jj++) accs[jj] = 0.f;
  for (int c = 0; c < 16; c++) {
    float qf[8];
#pragma unroll
    for (int e = 0; e < 8; e++) qf[e] = bf2f(qreg[c][e]);
#pragma unroll
    for (int jj = 0; jj < 16; jj++) {
      ushort8 kv = *(const ushort8*)&ks[j0 + jj][h * 128 + (c << 3)];
#pragma unroll
      for (int e = 0; e < 8; e++) accs[jj] += qf[e] * bf2f(kv[e]);
    }
  }
  const float scale = 0.088388347648318447f;  // 128^-0.5
#pragma unroll
  for (int jj = 0; jj < 16; jj++) sc[h][qi][j0 + jj] = accs[jj] * scale;
  __syncthreads();
  if (tid < 128) {     // softmax over valid keys, one thread per (head, query)
    int hh = tid >> 5, i = tid & 31;
    float m = -1e30f;
    for (int j = 0; j < cnt; j++) m = fmaxf(m, sc[hh][i][j]);
    float s = 0.f;
    for (int j = 0; j < cnt; j++) { float e = __expf(sc[hh][i][j] - m); sc[hh][i][j] = e; s += e; }
    for (int j = cnt; j < 32; j++) sc[hh][i][j] = 0.f;
    float inv = 1.f / s;
    for (int j = 0; j < 32; j++) sc[hh][i][j] *= inv;
  }
  __syncthreads();
  if (tid < 128) {     // wsum[h][j] = mean over valid queries
    int hh = tid >> 5, j = tid & 31;
    float s = 0.f;
    for (int i = 0; i < cnt; i++) s += sc[hh][i][j];
    wsum[hh][j] = s / (float)cnt;
  }
  __syncthreads();
  // z_h[e] = sum_j wsum[h][j] * emb[j][e]  (emb recomputed; zero rows skipped)
  for (int e = tid; e < 512; e += 256) {
    float za0 = 0.f, za1 = 0.f, za2 = 0.f, za3 = 0.f;
    for (int j = 0; j < cnt; j++) {
      float ev = byte_emb[(long)tok_s[j] * EE + e] + local_pos[(long)j * EE + e];
      za0 += wsum[0][j] * ev;
      za1 += wsum[1][j] * ev;
      za2 += wsum[2][j] * ev;
      za3 += wsum[3][j] * ev;
    }
    long zb = (long)pl * 2048;
    Z[zb + e]        = __float2bfloat16(za0);
    Z[zb + 512 + e]  = __float2bfloat16(za1);
    Z[zb + 1024 + e] = __float2bfloat16(za2);
    Z[zb + 1536 + e] = __float2bfloat16(za3);
  }
}

// ---------------------------------------------------------------------------
// Row LayerNorm: fp32 in, fp32 w/b; bf16 out (outb) or fp32 out (outf).
// ---------------------------------------------------------------------------
__global__ __launch_bounds__(256) void ln_kernel(
    const float* __restrict__ x, const float* __restrict__ w, const float* __restrict__ b,
    bf16* outb, float* outf, int N)
{
  __shared__ float red[8];
  __shared__ float mv[2];
  int row = blockIdx.x;
  const float* xr = x + (long)row * N;
  int tid = threadIdx.x, lane = tid & 63, wave = tid >> 6;
  float s = 0.f, s2 = 0.f;
  for (int c = tid; c < N; c += 256) { float v = xr[c]; s += v; s2 += v * v; }
  for (int o = 32; o; o >>= 1) { s += __shfl_down(s, o); s2 += __shfl_down(s2, o); }
  if (lane == 0) { red[wave] = s; red[4 + wave] = s2; }
  __syncthreads();
  if (tid == 0) {
    float ts = red[0] + red[1] + red[2] + red[3];
    float ts2 = red[4] + red[5] + red[6] + red[7];
    float mu = ts / N;
    float var = ts2 / N - mu * mu;
    mv[0] = mu; mv[1] = rsqrtf(var + 1e-5f);
  }
  __syncthreads();
  float mu = mv[0], rstd = mv[1];
  for (int c = tid; c < N; c += 256) {
    float v = (xr[c] - mu) * rstd * w[c] + b[c];
    if (outb) outb[(long)row * N + c] = __float2bfloat16(v);
    if (outf) outf[(long)row * N + c] = v;
  }
}

// ---------------------------------------------------------------------------
// Softmax over 1024 cols, scale folded in. fp32 scores -> bf16 probs IN PLACE
// (bf16 row written over the first half of the same fp32 row; all reads of the
// row complete before the barrier that precedes any write).
// ---------------------------------------------------------------------------
__global__ __launch_bounds__(256) void softmax_tr(float* __restrict__ S)
{
  __shared__ float red[4], red2[4];
  long row = blockIdx.x;
  float* sr = S + row * 1024;
  int tid = threadIdx.x, lane = tid & 63, wave = tid >> 6;
  const float scale = 0.10206207261596577f;  // 96^-0.5
  float v[4];
  float m = -1e30f;
#pragma unroll
  for (int k = 0; k < 4; k++) { v[k] = sr[tid + 256 * k] * scale; m = fmaxf(m, v[k]); }
  for (int o = 32; o; o >>= 1) m = fmaxf(m, __shfl_down(m, o));
  if (lane == 0) red[wave] = m;
  __syncthreads();
  m = fmaxf(fmaxf(red[0], red[1]), fmaxf(red[2], red[3]));
  float s = 0.f;
#pragma unroll
  for (int k = 0; k < 4; k++) { v[k] = __expf(v[k] - m); s += v[k]; }
  for (int o = 32; o; o >>= 1) s += __shfl_down(s, o);
  if (lane == 0) red2[wave] = s;
  __syncthreads();
  s = red2[0] + red2[1] + red2[2] + red2[3];
  float inv = 1.f / s;
  bf16* pr = (bf16*)sr;
#pragma unroll
  for (int k = 0; k < 4; k++) pr[tid + 256 * k] = __float2bfloat16(v[k] * inv);
}

// ---------------------------------------------------------------------------
// Vt[d][k] = qkv[k][1536 + d]  (V part), 32x32 LDS tiles. bf16.
// ---------------------------------------------------------------------------
__global__ __launch_bounds__(256) void transpose_v(
    const bf16* __restrict__ qkv, bf16* __restrict__ Vt)
{
  __shared__ u16 tile[32][33];
  int k0 = blockIdx.x << 5;
  int d0 = blockIdx.y << 5;
  int tx = threadIdx.x & 31, ty = threadIdx.x >> 5;
  const u16* q = (const u16*)qkv;
  for (int i = ty; i < 32; i += 8)
    tile[i][tx] = q[(long)(k0 + i) * 2304 + 1536 + d0 + tx];
  __syncthreads();
  u16* vt = (u16*)Vt;
  for (int i = ty; i < 32; i += 8)
    vt[(long)(d0 + i) * 1024 + k0 + tx] = tile[tx][i];
}

extern "C" void kernel_launch(void* const* d_in, const int* in_sizes, int n_in,
                              void* d_out, int out_size, void* d_ws, size_t ws_size,
                              hipStream_t stream)
{
  const int*   tokens    = (const int*)d_in[0];
  const int*   lengths   = (const int*)d_in[1];
  const float* byte_emb  = (const float*)d_in[2];
  const float* local_pos = (const float*)d_in[3];
  const float* patch_pos = (const float*)d_in[4];
  const float* pa_qkv_w  = (const float*)d_in[5];
  const float* pa_qkv_b  = (const float*)d_in[6];
  const float* pa_out_w  = (const float*)d_in[7];
  const float* pa_out_b  = (const float*)d_in[8];
  const float* proj_w    = (const float*)d_in[9];
  const float* proj_b    = (const float*)d_in[10];
  const float* Wqkv      = (const float*)d_in[11];
  const float* Bqkv      = (const float*)d_in[12];
  const float* Wout      = (const float*)d_in[13];
  const float* Bout      = (const float*)d_in[14];
  const float* ln1w      = (const float*)d_in[15];
  const float* ln1b      = (const float*)d_in[16];
  const float* ln2w      = (const float*)d_in[17];
  const float* ln2b      = (const float*)d_in[18];
  const float* W1        = (const float*)d_in[19];
  const float* B1        = (const float*)d_in[20];
  const float* W2        = (const float*)d_in[21];
  const float* B2        = (const float*)d_in[22];
  const float* lnfw      = (const float*)d_in[23];
  const float* lnfb      = (const float*)d_in[24];

  char* ws = (char*)d_ws;
  const size_t MB = 1ull << 20;
  bf16*  embC   = (bf16*)(ws);              // [0,8)    chunk emb [8192,512]
  bf16*  QKC    = (bf16*)(ws + 8 * MB);     // [8,24)   chunk Q|K [8192,1024]
  bf16*  Z      = (bf16*)(ws + 24 * MB);    // [24,28)  [1024,4,512]
  bf16*  o_mean = (bf16*)(ws + 28 * MB);    // [28,29)  [1024,512]
  bf16*  t1     = (bf16*)(ws + 29 * MB);    // [29,30)  [1024,512]
  float* h      = (float*)(ws + 30 * MB);   // [30,33)  [1024,768] fp32
  bf16*  hn     = (bf16*)(ws + 33 * MB);    // [33,35)  [1024,768]
  bf16*  qkvt   = (bf16*)(ws + 35 * MB);    // [35,40)  [1024,2304]
  bf16*  Vt     = (bf16*)(ws + 40 * MB);    // [40,42)  [768,1024]
  bf16*  attn   = (bf16*)(ws + 42 * MB);    // [42,44)  [1024,768]
  bf16*  ffb    = (bf16*)(ws + 44 * MB);    // [44,50)  [1024,3072]
  float* scores = (float*)(ws + 50 * MB);   // [50,82)  [8,1024,1024] fp32; probs bf16 in-place

  // ---- phase 1: patch encoder, 4 chunks of 256 patches ----
  for (int c = 0; c < 4; c++) {
    int p0 = c * 256, row0 = c * 8192;
    embed_kernel<<<8192, 256, 0, stream>>>(
        tokens + row0, lengths + p0, byte_emb, local_pos, embC);
    // QKC = embC @ Wqk^T + bqk   [8192,1024], Wqk = pa_qkv_w rows [0,1024)
    gemm_bt<true><<<dim3(16, 128, 1), 256, 0, stream>>>(
        embC, 0, EE, pa_qkv_w, 0, EE, nullptr, QKC, 0, 1024,
        pa_qkv_b, 0, nullptr, 8192, 1024, EE, 0);
    patch_attn<<<256, 256, 0, stream>>>(
        QKC, tokens + row0, lengths + p0, byte_emb, local_pos, Z + (long)p0 * 2048);
  }
  // o_mean[:, h*128:(h+1)*128] = Z[:,h,:] @ Wv_h^T + bv_h   (batched over 4 heads)
  gemm_bt<true><<<dim3(2, 16, 4), 256, 0, stream>>>(
      Z, 512, 2048, pa_qkv_w + 1024L * EE, 128L * EE, EE, nullptr, o_mean, 128, EE,
      pa_qkv_b + 1024, 128, nullptr, PP, 128, EE, 0);
  // t1 = o_mean @ pa_out_w^T + pa_out_b  [1024,512]
  gemm_bt<true><<<dim3(8, 16, 1), 256, 0, stream>>>(
      o_mean, 0, EE, pa_out_w, 0, EE, nullptr, t1, 0, EE,
      pa_out_b, 0, nullptr, PP, EE, EE, 0);
  // h = t1 @ proj_w^T + proj_b + patch_pos  [1024,768] fp32
  gemm_bt<true><<<dim3(12, 16, 1), 256, 0, stream>>>(
      t1, 0, EE, proj_w, 0, EE, h, nullptr, 0, DD,
      proj_b, 0, patch_pos, PP, DD, EE, 0);

  // ---- phase 2: transformer encoder ----
  for (int i = 0; i < NLAYER; i++) {
    ln_kernel<<<PP, 256, 0, stream>>>(h, ln1w + i * DD, ln1b + i * DD, hn, nullptr, DD);
    gemm_bt<true><<<dim3(36, 16, 1), 256, 0, stream>>>(
        hn, 0, DD, Wqkv + (long)i * 2304 * DD, 0, DD, nullptr, qkvt, 0, 2304,
        Bqkv + i * 2304, 0, nullptr, PP, 2304, DD, 0);
    // scores[h] = Q_h @ K_h^T  (8 heads batched, K=96)
    gemm_bt<false><<<dim3(16, 16, 8), 256, 0, stream>>>(
        qkvt, 96, 2304, qkvt + DD, 96, 2304, scores, nullptr, 1024L * 1024, 1024,
        nullptr, 0, nullptr, 1024, 1024, 96, 0);
    softmax_tr<<<8192, 256, 0, stream>>>(scores);
    transpose_v<<<dim3(32, 24), 256, 0, stream>>>(qkvt, Vt);
    // attn[:, h*96:(h+1)*96] = P_h @ V_h   (P bf16 in-place, element stride 2048)
    gemm_bt<false><<<dim3(2, 16, 8), 256, 0, stream>>>(
        (bf16*)scores, 1024L * 2048, 2048, Vt, 96L * 1024, 1024, nullptr, attn, 96, DD,
        nullptr, 0, nullptr, 1024, 96, 1024, 0);
    // h += attn @ Wout^T + bo
    gemm_bt<true><<<dim3(12, 16, 1), 256, 0, stream>>>(
        attn, 0, DD, Wout + (long)i * DD * DD, 0, DD, h, nullptr, 0, DD,
        Bout + i * DD, 0, h, PP, DD, DD, 0);
    ln_kernel<<<PP, 256, 0, stream>>>(h, ln2w + i * DD, ln2b + i * DD, hn, nullptr, DD);
    // ffb = gelu(hn @ W1^T + b1)  [1024,3072]
    gemm_bt<true><<<dim3(48, 16, 1), 256, 0, stream>>>(
        hn, 0, DD, W1 + (long)i * FFDIM * DD, 0, DD, nullptr, ffb, 0, FFDIM,
        B1 + i * FFDIM, 0, nullptr, PP, FFDIM, DD, 1);
    // h += ffb @ W2^T + b2
    gemm_bt<true><<<dim3(12, 16, 1), 256, 0, stream>>>(
        ffb, 0, FFDIM, W2 + (long)i * DD * FFDIM, 0, FFDIM, h, nullptr, 0, DD,
        B2 + i * DD, 0, h, PP, DD, FFDIM, 0);
  }
  ln_kernel<<<PP, 256, 0, stream>>>(h, lnfw, lnfb, nullptr, (float*)d_out, DD);
}

// Round 4
// 1778.345 us; speedup vs baseline: 1.0210x; 1.0210x over previous
//
#include <hip/hip_runtime.h>
#include <hip/hip_bf16.h>
#include <math.h>

typedef __hip_bfloat16 bf16;
typedef unsigned short u16;
typedef __attribute__((ext_vector_type(8))) short short8;
typedef __attribute__((ext_vector_type(8))) unsigned short ushort8;
typedef __attribute__((ext_vector_type(4))) float f32x4;

#define PP 1024
#define LL 32
#define EE 512
#define DD 768
#define NLAYER 6
#define FFDIM 3072

__device__ __forceinline__ float bf2f(u16 u) { return __uint_as_float(((unsigned)u) << 16); }
// fp32 -> bf16 (RNE), finite inputs only
__device__ __forceinline__ u16 f2b(float x) {
  unsigned u = __float_as_uint(x);
  return (u16)((u + 0x7FFFu + ((u >> 16) & 1u)) >> 16);
}

// ---------------------------------------------------------------------------
// emb[pl][:] = (l < len[p]) ? byte_emb[tok] + local_pos[l] : 0  (fp32 in, bf16 out)
// ---------------------------------------------------------------------------
__global__ __launch_bounds__(256) void embed_kernel(
    const int* __restrict__ tokens, const int* __restrict__ lengths,
    const float* __restrict__ byte_emb, const float* __restrict__ local_pos,
    bf16* __restrict__ emb)
{
  int pl = blockIdx.x;
  int p = pl >> 5, l = pl & 31;
  bool valid = l < lengths[p];
  int tok = tokens[pl];
  const float* be = byte_emb + (long)tok * EE;
  const float* lp = local_pos + (long)l * EE;
  u16* out = (u16*)emb + (long)pl * EE;
  for (int e = threadIdx.x; e < EE; e += 256) {
    float v = valid ? be[e] + lp[e] : 0.f;
    out[e] = f2b(v);
  }
}

// ---------------------------------------------------------------------------
// C = A @ B^T (+bias)(+addf)(gelu). A bf16 [M,K]; B [N,K] bf16 or fp32 per
// template (fp32 converted to bf16 during LDS staging). fp32 accum.
// 64x64 tile / 256 threads, BK=64, double-buffered LDS, one barrier per
// chunk, next chunk's global loads issued before this chunk's MFMAs.
// blockIdx.x = m-tile (fastest): weight n-tiles stay L2-resident, reused 16x.
// M % 64 == 0; N, K guarded (K tail of 32).
// Batched via blockIdx.z (element strides sAb/sBb/sCb; col offset via sCb).
// ---------------------------------------------------------------------------
template<bool BF32>
__global__ __launch_bounds__(256) void gemm64(
    const bf16* A, long sAb, int lda,
    const void* Bv, long sBb, int ldb,
    float* Cf, bf16* Cb, long sCb, int ldc,
    const float* bias, int biasStride,
    const float* addf,
    int M, int N, int K, int act)
{
  __shared__ u16 As[2][64][72];   // stride 144 B: 16B-aligned, 2-way-only banks
  __shared__ u16 Bs[2][64][72];
  const int bz = blockIdx.z;
  const u16* Ap = (const u16*)A + (long)bz * sAb;
  const u16* Bph = (const u16*)Bv + (long)bz * sBb;
  const float* Bpf = (const float*)Bv + (long)bz * sBb;
  const long coff = (long)bz * sCb;
  const int m0 = blockIdx.x << 6, n0 = blockIdx.y << 6;
  const int tid = threadIdx.x;
  const int wave = tid >> 6, lane = tid & 63;
  const int sr = tid >> 3;          // staging row 0..31 (and +32)
  const int scc = (tid & 7) << 3;   // staging col 0..56
  const int br0 = n0 + sr, br1 = n0 + sr + 32;
  const short8 zz = {0,0,0,0,0,0,0,0};
  f32x4 acc[4] = {{0.f,0.f,0.f,0.f},{0.f,0.f,0.f,0.f},{0.f,0.f,0.f,0.f},{0.f,0.f,0.f,0.f}};

#define LOADB(row, kk, dest)                                                   \
  do {                                                                         \
    if (BF32) {                                                                \
      const float* bp = Bpf + (long)(row) * ldb + (kk);                        \
      float4 x0 = *(const float4*)bp;                                          \
      float4 x1 = *(const float4*)(bp + 4);                                    \
      dest[0] = (short)f2b(x0.x); dest[1] = (short)f2b(x0.y);                  \
      dest[2] = (short)f2b(x0.z); dest[3] = (short)f2b(x0.w);                  \
      dest[4] = (short)f2b(x1.x); dest[5] = (short)f2b(x1.y);                  \
      dest[6] = (short)f2b(x1.z); dest[7] = (short)f2b(x1.w);                  \
    } else {                                                                   \
      dest = *(const short8*)(Bph + (long)(row) * ldb + (kk));                 \
    }                                                                          \
  } while (0)

  // prologue: stage chunk 0 into buffer 0
  {
    int ch = K < 64 ? K : 64;
    bool kv = scc < ch;
    short8 a0 = kv ? *(const short8*)(Ap + (long)(m0 + sr) * lda + scc) : zz;
    short8 a1 = kv ? *(const short8*)(Ap + (long)(m0 + sr + 32) * lda + scc) : zz;
    short8 b0 = zz, b1 = zz;
    if (kv && br0 < N) LOADB(br0, scc, b0);
    if (kv && br1 < N) LOADB(br1, scc, b1);
    *(short8*)&As[0][sr][scc] = a0;
    *(short8*)&As[0][sr + 32][scc] = a1;
    *(short8*)&Bs[0][sr][scc] = b0;
    *(short8*)&Bs[0][sr + 32][scc] = b1;
  }
  __syncthreads();

  const int arow = (wave << 4) + (lane & 15);
  const int kq = (lane >> 4) << 3;
  int buf = 0;
  for (int k0 = 0; k0 < K; k0 += 64) {
    int knext = k0 + 64;
    bool more = knext < K;
    short8 a0 = zz, a1 = zz, b0 = zz, b1 = zz;
    if (more) {   // issue next chunk's loads before MFMAs (overlap)
      int ch = K - knext; if (ch > 64) ch = 64;
      bool kv = scc < ch;
      if (kv) {
        a0 = *(const short8*)(Ap + (long)(m0 + sr) * lda + knext + scc);
        a1 = *(const short8*)(Ap + (long)(m0 + sr + 32) * lda + knext + scc);
        if (br0 < N) LOADB(br0, knext + scc, b0);
        if (br1 < N) LOADB(br1, knext + scc, b1);
      }
    }
    int rem = K - k0; if (rem > 64) rem = 64;
    {
      short8 af = *(const short8*)&As[buf][arow][kq];
#pragma unroll
      for (int nt = 0; nt < 4; nt++) {
        short8 bfr = *(const short8*)&Bs[buf][(nt << 4) + (lane & 15)][kq];
        acc[nt] = __builtin_amdgcn_mfma_f32_16x16x32_bf16(af, bfr, acc[nt], 0, 0, 0);
      }
    }
    if (rem > 32) {
      short8 af = *(const short8*)&As[buf][arow][32 + kq];
#pragma unroll
      for (int nt = 0; nt < 4; nt++) {
        short8 bfr = *(const short8*)&Bs[buf][(nt << 4) + (lane & 15)][32 + kq];
        acc[nt] = __builtin_amdgcn_mfma_f32_16x16x32_bf16(af, bfr, acc[nt], 0, 0, 0);
      }
    }
    if (more) {
      int nb = buf ^ 1;
      *(short8*)&As[nb][sr][scc] = a0;
      *(short8*)&As[nb][sr + 32][scc] = a1;
      *(short8*)&Bs[nb][sr][scc] = b0;
      *(short8*)&Bs[nb][sr + 32][scc] = b1;
      __syncthreads();
      buf = nb;
    }
  }
#undef LOADB

  int rbase = m0 + (wave << 4) + ((lane >> 4) << 2);
#pragma unroll
  for (int nt = 0; nt < 4; nt++) {
    int c = n0 + (nt << 4) + (lane & 15);
    if (c >= N) continue;
    float bvl = bias ? bias[bz * biasStride + c] : 0.f;
#pragma unroll
    for (int j = 0; j < 4; j++) {
      int r = rbase + j;
      long idx = coff + (long)r * ldc + c;
      float v = acc[nt][j] + bvl;
      if (addf) v += addf[idx];
      if (act == 1) v = 0.5f * v * (1.f + erff(v * 0.70710678118654752f));
      if (Cf) Cf[idx] = v;
      if (Cb) Cb[idx] = __float2bfloat16(v);
    }
  }
}

// ---------------------------------------------------------------------------
// Per-patch MHA over 32 bytes (4 heads, d=128) fused with masked mean;
// V path commuted: z_h = wsum_h @ emb (emb recomputed from fp32 tables).
// ---------------------------------------------------------------------------
__global__ __launch_bounds__(256) void patch_attn(
    const bf16* __restrict__ qk,
    const int* __restrict__ tokens, const int* __restrict__ lengths,
    const float* __restrict__ byte_emb, const float* __restrict__ local_pos,
    bf16* __restrict__ Z)
{
  __shared__ u16 ks[32][512];
  __shared__ float sc[4][32][32];
  __shared__ float wsum[4][32];
  __shared__ int tok_s[32];
  __shared__ int cnt_s;
  int pl = blockIdx.x;
  int tid = threadIdx.x;
  if (tid < 32) tok_s[tid] = tokens[pl * 32 + tid];
  if (tid == 0) cnt_s = lengths[pl];
  const u16* base = (const u16*)qk + (long)pl * 32 * 1024;
  for (int idx = tid; idx < 2048; idx += 256) {
    int r = idx >> 6, c = (idx & 63) << 3;
    *(uint4*)&ks[r][c] = *(const uint4*)(base + r * 1024 + 512 + c);
  }
  int h = tid >> 6, lane = tid & 63;
  int qi = lane >> 1;
  int j0 = (lane & 1) << 4;
  ushort8 qreg[16];
  const u16* qp = base + qi * 1024 + h * 128;
#pragma unroll
  for (int c = 0; c < 16; c++) qreg[c] = *(const ushort8*)(qp + (c << 3));
  __syncthreads();
  int cnt = cnt_s;
  float accs[16];
#pragma unroll
  for (int jj = 0; jj < 16; jj++) accs[jj] = 0.f;
  for (int c = 0; c < 16; c++) {
    float qf[8];
#pragma unroll
    for (int e = 0; e < 8; e++) qf[e] = bf2f(qreg[c][e]);
#pragma unroll
    for (int jj = 0; jj < 16; jj++) {
      ushort8 kv = *(const ushort8*)&ks[j0 + jj][h * 128 + (c << 3)];
#pragma unroll
      for (int e = 0; e < 8; e++) accs[jj] += qf[e] * bf2f(kv[e]);
    }
  }
  const float scale = 0.088388347648318447f;
#pragma unroll
  for (int jj = 0; jj < 16; jj++) sc[h][qi][j0 + jj] = accs[jj] * scale;
  __syncthreads();
  if (tid < 128) {
    int hh = tid >> 5, i = tid & 31;
    float m = -1e30f;
    for (int j = 0; j < cnt; j++) m = fmaxf(m, sc[hh][i][j]);
    float s = 0.f;
    for (int j = 0; j < cnt; j++) { float e = __expf(sc[hh][i][j] - m); sc[hh][i][j] = e; s += e; }
    for (int j = cnt; j < 32; j++) sc[hh][i][j] = 0.f;
    float inv = 1.f / s;
    for (int j = 0; j < 32; j++) sc[hh][i][j] *= inv;
  }
  __syncthreads();
  if (tid < 128) {
    int hh = tid >> 5, j = tid & 31;
    float s = 0.f;
    for (int i = 0; i < cnt; i++) s += sc[hh][i][j];
    wsum[hh][j] = s / (float)cnt;
  }
  __syncthreads();
  for (int e = tid; e < 512; e += 256) {
    float za0 = 0.f, za1 = 0.f, za2 = 0.f, za3 = 0.f;
    for (int j = 0; j < cnt; j++) {
      float ev = byte_emb[(long)tok_s[j] * EE + e] + local_pos[(long)j * EE + e];
      za0 += wsum[0][j] * ev;
      za1 += wsum[1][j] * ev;
      za2 += wsum[2][j] * ev;
      za3 += wsum[3][j] * ev;
    }
    long zb = (long)pl * 2048;
    Z[zb + e]        = __float2bfloat16(za0);
    Z[zb + 512 + e]  = __float2bfloat16(za1);
    Z[zb + 1024 + e] = __float2bfloat16(za2);
    Z[zb + 1536 + e] = __float2bfloat16(za3);
  }
}

// ---------------------------------------------------------------------------
// Row LayerNorm: fp32 in, fp32 w/b; bf16 out (outb) or fp32 out (outf).
// ---------------------------------------------------------------------------
__global__ __launch_bounds__(256) void ln_kernel(
    const float* __restrict__ x, const float* __restrict__ w, const float* __restrict__ b,
    bf16* outb, float* outf, int N)
{
  __shared__ float red[8];
  __shared__ float mv[2];
  int row = blockIdx.x;
  const float* xr = x + (long)row * N;
  int tid = threadIdx.x, lane = tid & 63, wave = tid >> 6;
  float s = 0.f, s2 = 0.f;
  for (int c = tid; c < N; c += 256) { float v = xr[c]; s += v; s2 += v * v; }
  for (int o = 32; o; o >>= 1) { s += __shfl_down(s, o); s2 += __shfl_down(s2, o); }
  if (lane == 0) { red[wave] = s; red[4 + wave] = s2; }
  __syncthreads();
  if (tid == 0) {
    float ts = red[0] + red[1] + red[2] + red[3];
    float ts2 = red[4] + red[5] + red[6] + red[7];
    float mu = ts / N;
    float var = ts2 / N - mu * mu;
    mv[0] = mu; mv[1] = rsqrtf(var + 1e-5f);
  }
  __syncthreads();
  float mu = mv[0], rstd = mv[1];
  for (int c = tid; c < N; c += 256) {
    float v = (xr[c] - mu) * rstd * w[c] + b[c];
    if (outb) outb[(long)row * N + c] = __float2bfloat16(v);
    if (outf) outf[(long)row * N + c] = v;
  }
}

// ---------------------------------------------------------------------------
// Softmax over 1024 cols, in place on bf16 logits (scale folded in).
// ---------------------------------------------------------------------------
__global__ __launch_bounds__(256) void softmax_bf(u16* __restrict__ S)
{
  __shared__ float red[4], red2[4];
  long row = blockIdx.x;
  u16* sr = S + row * 1024;
  int tid = threadIdx.x, lane = tid & 63, wave = tid >> 6;
  const float scale = 0.10206207261596577f;  // 96^-0.5
  ushort4 raw = *(const ushort4*)(sr + tid * 4);
  float v[4] = {bf2f(raw.x) * scale, bf2f(raw.y) * scale, bf2f(raw.z) * scale, bf2f(raw.w) * scale};
  float m = fmaxf(fmaxf(v[0], v[1]), fmaxf(v[2], v[3]));
  for (int o = 32; o; o >>= 1) m = fmaxf(m, __shfl_down(m, o));
  if (lane == 0) red[wave] = m;
  __syncthreads();
  m = fmaxf(fmaxf(red[0], red[1]), fmaxf(red[2], red[3]));
  float s = 0.f;
#pragma unroll
  for (int k = 0; k < 4; k++) { v[k] = __expf(v[k] - m); s += v[k]; }
  for (int o = 32; o; o >>= 1) s += __shfl_down(s, o);
  if (lane == 0) red2[wave] = s;
  __syncthreads();
  s = red2[0] + red2[1] + red2[2] + red2[3];
  float inv = 1.f / s;
  ushort4 o4;
  o4.x = f2b(v[0] * inv); o4.y = f2b(v[1] * inv); o4.z = f2b(v[2] * inv); o4.w = f2b(v[3] * inv);
  *(ushort4*)(sr + tid * 4) = o4;
}

// ---------------------------------------------------------------------------
// Vt[d][k] = qkv[k][1536 + d]  (V part), 32x32 LDS tiles. bf16.
// ---------------------------------------------------------------------------
__global__ __launch_bounds__(256) void transpose_v(
    const bf16* __restrict__ qkv, bf16* __restrict__ Vt)
{
  __shared__ u16 tile[32][33];
  int k0 = blockIdx.x << 5;
  int d0 = blockIdx.y << 5;
  int tx = threadIdx.x & 31, ty = threadIdx.x >> 5;
  const u16* q = (const u16*)qkv;
  for (int i = ty; i < 32; i += 8)
    tile[i][tx] = q[(long)(k0 + i) * 2304 + 1536 + d0 + tx];
  __syncthreads();
  u16* vt = (u16*)Vt;
  for (int i = ty; i < 32; i += 8)
    vt[(long)(d0 + i) * 1024 + k0 + tx] = tile[tx][i];
}

extern "C" void kernel_launch(void* const* d_in, const int* in_sizes, int n_in,
                              void* d_out, int out_size, void* d_ws, size_t ws_size,
                              hipStream_t stream)
{
  const int*   tokens    = (const int*)d_in[0];
  const int*   lengths   = (const int*)d_in[1];
  const float* byte_emb  = (const float*)d_in[2];
  const float* local_pos = (const float*)d_in[3];
  const float* patch_pos = (const float*)d_in[4];
  const float* pa_qkv_w  = (const float*)d_in[5];
  const float* pa_qkv_b  = (const float*)d_in[6];
  const float* pa_out_w  = (const float*)d_in[7];
  const float* pa_out_b  = (const float*)d_in[8];
  const float* proj_w    = (const float*)d_in[9];
  const float* proj_b    = (const float*)d_in[10];
  const float* Wqkv      = (const float*)d_in[11];
  const float* Bqkv      = (const float*)d_in[12];
  const float* Wout      = (const float*)d_in[13];
  const float* Bout      = (const float*)d_in[14];
  const float* ln1w      = (const float*)d_in[15];
  const float* ln1b      = (const float*)d_in[16];
  const float* ln2w      = (const float*)d_in[17];
  const float* ln2b      = (const float*)d_in[18];
  const float* W1        = (const float*)d_in[19];
  const float* B1        = (const float*)d_in[20];
  const float* W2        = (const float*)d_in[21];
  const float* B2        = (const float*)d_in[22];
  const float* lnfw      = (const float*)d_in[23];
  const float* lnfb      = (const float*)d_in[24];

  char* ws = (char*)d_ws;
  const size_t MB = 1ull << 20;
  // total ws footprint 66 MB (round-2's 82 MB layout passed; stay under it)
  bf16*  embC   = (bf16*)(ws);              // [0,8)    phase1 chunk emb [8192,512]
  bf16*  QKC    = (bf16*)(ws + 8 * MB);     // [8,24)   phase1 chunk Q|K [8192,1024]
  bf16*  Z      = (bf16*)(ws + 24 * MB);    // [24,28)  [1024,4,512]
  bf16*  o_mean = (bf16*)(ws + 28 * MB);    // [28,29)
  bf16*  t1     = (bf16*)(ws + 29 * MB);    // [29,30)
  float* h      = (float*)(ws + 30 * MB);   // [30,33)  [1024,768] fp32
  bf16*  hn     = (bf16*)(ws + 33 * MB);    // [33,35)
  bf16*  qkvt   = (bf16*)(ws + 35 * MB);    // [35,40)  [1024,2304]
  bf16*  Vt     = (bf16*)(ws + 40 * MB);    // [40,42)  [768,1024]
  bf16*  attn   = (bf16*)(ws + 42 * MB);    // [42,44)  [1024,768]
  bf16*  ffb    = (bf16*)(ws + 44 * MB);    // [44,50)  [1024,3072]
  u16*   scores = (u16*)(ws + 50 * MB);     // [50,66)  bf16 [8,1024,1024]

  // ---- phase 1: patch encoder, 4 chunks of 256 patches ----
  for (int c = 0; c < 4; c++) {
    int p0 = c * 256, row0 = c * 8192;
    embed_kernel<<<8192, 256, 0, stream>>>(
        tokens + row0, lengths + p0, byte_emb, local_pos, embC);
    // QKC = embC @ Wqk^T + bqk  [8192,1024]
    gemm64<true><<<dim3(128, 16, 1), 256, 0, stream>>>(
        embC, 0, EE, pa_qkv_w, 0, EE, nullptr, QKC, 0, 1024,
        pa_qkv_b, 0, nullptr, 8192, 1024, EE, 0);
    patch_attn<<<256, 256, 0, stream>>>(
        QKC, tokens + row0, lengths + p0, byte_emb, local_pos, Z + (long)p0 * 2048);
  }
  // o_mean[:, h*128:(h+1)*128] = Z[:,h,:] @ Wv_h^T + bv_h
  gemm64<true><<<dim3(16, 2, 4), 256, 0, stream>>>(
      Z, 512, 2048, pa_qkv_w + 1024L * EE, 128L * EE, EE,
      nullptr, o_mean, 128, EE, pa_qkv_b + 1024, 128, nullptr, PP, 128, EE, 0);
  // t1 = o_mean @ pa_out_w^T + b
  gemm64<true><<<dim3(16, 8, 1), 256, 0, stream>>>(
      o_mean, 0, EE, pa_out_w, 0, EE, nullptr, t1, 0, EE,
      pa_out_b, 0, nullptr, PP, EE, EE, 0);
  // h = t1 @ proj_w^T + b + patch_pos (fp32)
  gemm64<true><<<dim3(16, 12, 1), 256, 0, stream>>>(
      t1, 0, EE, proj_w, 0, EE, h, nullptr, 0, DD,
      proj_b, 0, patch_pos, PP, DD, EE, 0);

  // ---- phase 2: transformer encoder ----
  for (int i = 0; i < NLAYER; i++) {
    ln_kernel<<<PP, 256, 0, stream>>>(h, ln1w + i * DD, ln1b + i * DD, hn, nullptr, DD);
    gemm64<true><<<dim3(16, 36, 1), 256, 0, stream>>>(
        hn, 0, DD, Wqkv + (long)i * 2304 * DD, 0, DD, nullptr, qkvt, 0, 2304,
        Bqkv + i * 2304, 0, nullptr, PP, 2304, DD, 0);
    // scores[h] = Q_h @ K_h^T (bf16 logits)
    gemm64<false><<<dim3(16, 16, 8), 256, 0, stream>>>(
        qkvt, 96, 2304, qkvt + DD, 96, 2304, nullptr, (bf16*)scores, 1024L * 1024, 1024,
        nullptr, 0, nullptr, 1024, 1024, 96, 0);
    softmax_bf<<<8192, 256, 0, stream>>>(scores);
    transpose_v<<<dim3(32, 24), 256, 0, stream>>>(qkvt, Vt);
    // attn[:, h*96:(h+1)*96] = P_h @ V_h
    gemm64<false><<<dim3(16, 2, 8), 256, 0, stream>>>(
        (bf16*)scores, 1024L * 1024, 1024, Vt, 96L * 1024, 1024, nullptr, attn, 96, DD,
        nullptr, 0, nullptr, 1024, 96, 1024, 0);
    // h += attn @ Wout^T + bo
    gemm64<true><<<dim3(16, 12, 1), 256, 0, stream>>>(
        attn, 0, DD, Wout + (long)i * DD * DD, 0, DD, h, nullptr, 0, DD,
        Bout + i * DD, 0, h, PP, DD, DD, 0);
    ln_kernel<<<PP, 256, 0, stream>>>(h, ln2w + i * DD, ln2b + i * DD, hn, nullptr, DD);
    // ffb = gelu(hn @ W1^T + b1)
    gemm64<true><<<dim3(16, 48, 1), 256, 0, stream>>>(
        hn, 0, DD, W1 + (long)i * FFDIM * DD, 0, DD, nullptr, ffb, 0, FFDIM,
        B1 + i * FFDIM, 0, nullptr, PP, FFDIM, DD, 1);
    // h += ffb @ W2^T + b2
    gemm64<true><<<dim3(16, 12, 1), 256, 0, stream>>>(
        ffb, 0, FFDIM, W2 + (long)i * DD * FFDIM, 0, FFDIM, h, nullptr, 0, DD,
        B2 + i * DD, 0, h, PP, DD, FFDIM, 0);
  }
  ln_kernel<<<PP, 256, 0, stream>>>(h, lnfw, lnfb, nullptr, (float*)d_out, DD);
}

// Round 5
// 1216.499 us; speedup vs baseline: 1.4925x; 1.4619x over previous
//
#include <hip/hip_runtime.h>
#include <hip/hip_bf16.h>
#include <math.h>

typedef __hip_bfloat16 bf16;
typedef unsigned short u16;
typedef __attribute__((ext_vector_type(8))) short short8;
typedef __attribute__((ext_vector_type(4))) float f32x4;

#define PP 1024
#define LL 32
#define EE 512
#define DD 768
#define NLAYER 6
#define FFDIM 3072

__device__ __forceinline__ float bf2f(u16 u) { return __uint_as_float(((unsigned)u) << 16); }
// fp32 -> bf16 (RNE), finite inputs only
__device__ __forceinline__ u16 f2b(float x) {
  unsigned u = __float_as_uint(x);
  return (u16)((u + 0x7FFFu + ((u >> 16) & 1u)) >> 16);
}

// ---------------------------------------------------------------------------
// 4-region fp32 -> bf16 bulk convert. Region picked by blockIdx.y; counts in
// float4 units. Unused regions: n=0.
// ---------------------------------------------------------------------------
__global__ __launch_bounds__(256) void cvt4(
    const float* s0, const float* s1, const float* s2, const float* s3,
    u16* d0, u16* d1, u16* d2, u16* d3,
    int n0, int n1, int n2, int n3)
{
  int r = blockIdx.y;
  const float* s = r == 0 ? s0 : r == 1 ? s1 : r == 2 ? s2 : s3;
  u16* d        = r == 0 ? d0 : r == 1 ? d1 : r == 2 ? d2 : d3;
  int n4        = r == 0 ? n0 : r == 1 ? n1 : r == 2 ? n2 : n3;
  int i = blockIdx.x * 256 + threadIdx.x;
  if (i < n4) {
    float4 v = ((const float4*)s)[i];
    ushort4 o;
    o.x = f2b(v.x); o.y = f2b(v.y); o.z = f2b(v.z); o.w = f2b(v.w);
    ((ushort4*)d)[i] = o;
  }
}

// ---------------------------------------------------------------------------
// C = A @ B^T (+bias)(+addf)(gelu). A bf16 [M,K] (or fused byte-embedding
// when AEMB: A[row][k] = valid ? byte_emb[tok[row]][k]+local_pos[row&31][k] : 0,
// fp32 tables, converted in staging). B bf16 [N,K]. fp32 accum.
// 64x64 tile / 256 threads, BK=64, double-buffered LDS, one barrier per
// chunk, next chunk's global loads issued before this chunk's MFMAs.
// blockIdx.x = m-tile (fastest): weight n-tiles stay L2-resident.
// M % 64 == 0; N, K guarded (K tail of 32).
// Batched via blockIdx.z (element strides sAb/sBb/sCb; col offset via sCb).
// ---------------------------------------------------------------------------
template<bool AEMB>
__global__ __launch_bounds__(256) void gemm64(
    const bf16* A, long sAb, int lda,
    const bf16* B, long sBb, int ldb,
    float* Cf, bf16* Cb, long sCb, int ldc,
    const float* bias, int biasStride,
    const float* addf,
    int M, int N, int K, int act,
    const int* tokens, const int* lengths,
    const float* be, const float* lp)
{
  __shared__ u16 As[2][64][72];   // stride 144 B: 16B-aligned, 2-way-only banks
  __shared__ u16 Bs[2][64][72];
  const int bz = blockIdx.z;
  const u16* Ap = (const u16*)A + (long)bz * sAb;
  const u16* Bp = (const u16*)B + (long)bz * sBb;
  const long coff = (long)bz * sCb;
  const int m0 = blockIdx.x << 6, n0 = blockIdx.y << 6;
  const int tid = threadIdx.x;
  const int wave = tid >> 6, lane = tid & 63;
  const int sr = tid >> 3;          // staging row 0..31 (and +32)
  const int scc = (tid & 7) << 3;   // staging col 0..56
  const int br0 = n0 + sr, br1 = n0 + sr + 32;
  const short8 zz = {0,0,0,0,0,0,0,0};
  f32x4 acc[4] = {{0.f,0.f,0.f,0.f},{0.f,0.f,0.f,0.f},{0.f,0.f,0.f,0.f},{0.f,0.f,0.f,0.f}};

#define LOADA(row, kk, dest)                                                   \
  do {                                                                         \
    if (!AEMB) {                                                               \
      dest = *(const short8*)(Ap + (long)(row) * lda + (kk));                  \
    } else {                                                                   \
      int rr = (row); int ll = rr & 31;                                        \
      if (ll < lengths[rr >> 5]) {                                             \
        const float* bpp = be + ((long)tokens[rr] << 9) + (kk);                \
        const float* lpp = lp + ((long)ll << 9) + (kk);                        \
        float4 x0 = *(const float4*)bpp, x1 = *(const float4*)(bpp + 4);       \
        float4 y0 = *(const float4*)lpp, y1 = *(const float4*)(lpp + 4);       \
        dest[0] = (short)f2b(x0.x + y0.x); dest[1] = (short)f2b(x0.y + y0.y);  \
        dest[2] = (short)f2b(x0.z + y0.z); dest[3] = (short)f2b(x0.w + y0.w);  \
        dest[4] = (short)f2b(x1.x + y1.x); dest[5] = (short)f2b(x1.y + y1.y);  \
        dest[6] = (short)f2b(x1.z + y1.z); dest[7] = (short)f2b(x1.w + y1.w);  \
      } else dest = zz;                                                        \
    }                                                                          \
  } while (0)

  // prologue: stage chunk 0 into buffer 0
  {
    int ch = K < 64 ? K : 64;
    bool kv = scc < ch;
    short8 a0 = zz, a1 = zz, b0 = zz, b1 = zz;
    if (kv) {
      LOADA(m0 + sr, scc, a0);
      LOADA(m0 + sr + 32, scc, a1);
      if (br0 < N) b0 = *(const short8*)(Bp + (long)br0 * ldb + scc);
      if (br1 < N) b1 = *(const short8*)(Bp + (long)br1 * ldb + scc);
    }
    *(short8*)&As[0][sr][scc] = a0;
    *(short8*)&As[0][sr + 32][scc] = a1;
    *(short8*)&Bs[0][sr][scc] = b0;
    *(short8*)&Bs[0][sr + 32][scc] = b1;
  }
  __syncthreads();

  const int arow = (wave << 4) + (lane & 15);
  const int kq = (lane >> 4) << 3;
  int buf = 0;
  for (int k0 = 0; k0 < K; k0 += 64) {
    int knext = k0 + 64;
    bool more = knext < K;
    short8 a0 = zz, a1 = zz, b0 = zz, b1 = zz;
    if (more) {   // issue next chunk's loads before MFMAs (overlap)
      int ch = K - knext; if (ch > 64) ch = 64;
      bool kv = scc < ch;
      if (kv) {
        LOADA(m0 + sr, knext + scc, a0);
        LOADA(m0 + sr + 32, knext + scc, a1);
        if (br0 < N) b0 = *(const short8*)(Bp + (long)br0 * ldb + knext + scc);
        if (br1 < N) b1 = *(const short8*)(Bp + (long)br1 * ldb + knext + scc);
      }
    }
    int rem = K - k0; if (rem > 64) rem = 64;
    {
      short8 af = *(const short8*)&As[buf][arow][kq];
#pragma unroll
      for (int nt = 0; nt < 4; nt++) {
        short8 bfr = *(const short8*)&Bs[buf][(nt << 4) + (lane & 15)][kq];
        acc[nt] = __builtin_amdgcn_mfma_f32_16x16x32_bf16(af, bfr, acc[nt], 0, 0, 0);
      }
    }
    if (rem > 32) {
      short8 af = *(const short8*)&As[buf][arow][32 + kq];
#pragma unroll
      for (int nt = 0; nt < 4; nt++) {
        short8 bfr = *(const short8*)&Bs[buf][(nt << 4) + (lane & 15)][32 + kq];
        acc[nt] = __builtin_amdgcn_mfma_f32_16x16x32_bf16(af, bfr, acc[nt], 0, 0, 0);
      }
    }
    if (more) {
      int nb = buf ^ 1;
      *(short8*)&As[nb][sr][scc] = a0;
      *(short8*)&As[nb][sr + 32][scc] = a1;
      *(short8*)&Bs[nb][sr][scc] = b0;
      *(short8*)&Bs[nb][sr + 32][scc] = b1;
      __syncthreads();
      buf = nb;
    }
  }
#undef LOADA

  int rbase = m0 + (wave << 4) + ((lane >> 4) << 2);
#pragma unroll
  for (int nt = 0; nt < 4; nt++) {
    int c = n0 + (nt << 4) + (lane & 15);
    if (c >= N) continue;
    float bvl = bias ? bias[bz * biasStride + c] : 0.f;
#pragma unroll
    for (int j = 0; j < 4; j++) {
      int r = rbase + j;
      long idx = coff + (long)r * ldc + c;
      float v = acc[nt][j] + bvl;
      if (addf) v += addf[idx];
      if (act == 1) v = 0.5f * v * (1.f + erff(v * 0.70710678118654752f));
      if (Cf) Cf[idx] = v;
      if (Cb) Cb[idx] = __float2bfloat16(v);
    }
  }
}

// ---------------------------------------------------------------------------
// Per-patch MHA over 32 bytes (4 heads, d=128) fused with masked mean.
// MFMA QK^T (no LDS, no spills): wave = head; 2x2 16x16 C-tiles, 4 k-chunks.
// Softmax + column-mean via shuffle reductions in MFMA C-layout
// (row = (lane>>4)*4 + reg + ti*16, col = (lane&15) + tj*16).
// V path commuted: z_h = wsum_h @ emb (emb recomputed from fp32 tables).
// ---------------------------------------------------------------------------
__global__ __launch_bounds__(256) void patch_attn(
    const bf16* __restrict__ qk,   // [32768, 1024] = [Q|K]
    const int* __restrict__ tokens, const int* __restrict__ lengths,
    const float* __restrict__ byte_emb, const float* __restrict__ local_pos,
    bf16* __restrict__ Z)          // [1024, 4, 512]
{
  __shared__ float wsum[4][32];
  __shared__ int tok_s[32];
  __shared__ int cnt_s;
  int p = blockIdx.x;
  int tid = threadIdx.x;
  if (tid < 32) tok_s[tid] = tokens[p * 32 + tid];
  if (tid == 0) cnt_s = lengths[p];
  __syncthreads();
  int cnt = cnt_s;
  int h = tid >> 6, lane = tid & 63;
  const u16* base = (const u16*)qk + (long)p * 32 * 1024 + h * 128;
  const int rsel = lane & 15;
  const int ksel = (lane >> 4) << 3;

  f32x4 acc[2][2] = {{{0.f,0.f,0.f,0.f},{0.f,0.f,0.f,0.f}},
                     {{0.f,0.f,0.f,0.f},{0.f,0.f,0.f,0.f}}};
#pragma unroll
  for (int kc = 0; kc < 4; kc++) {
    int ko = kc * 32 + ksel;
    short8 a0 = *(const short8*)(base + (long)rsel * 1024 + ko);
    short8 a1 = *(const short8*)(base + (long)(16 + rsel) * 1024 + ko);
    short8 b0 = *(const short8*)(base + 512 + (long)rsel * 1024 + ko);
    short8 b1 = *(const short8*)(base + 512 + (long)(16 + rsel) * 1024 + ko);
    acc[0][0] = __builtin_amdgcn_mfma_f32_16x16x32_bf16(a0, b0, acc[0][0], 0, 0, 0);
    acc[0][1] = __builtin_amdgcn_mfma_f32_16x16x32_bf16(a0, b1, acc[0][1], 0, 0, 0);
    acc[1][0] = __builtin_amdgcn_mfma_f32_16x16x32_bf16(a1, b0, acc[1][0], 0, 0, 0);
    acc[1][1] = __builtin_amdgcn_mfma_f32_16x16x32_bf16(a1, b1, acc[1][1], 0, 0, 0);
  }

  const float scale = 0.088388347648318447f;  // 128^-0.5
  int j0 = lane & 15, j1 = 16 + j0;
  bool v0 = j0 < cnt, v1 = j1 < cnt;
  int rowq = (lane >> 4) << 2;
  float cs0 = 0.f, cs1 = 0.f;   // column-sum partials for cols j0, j1
#pragma unroll
  for (int ti = 0; ti < 2; ti++) {
    float s0[4], s1[4], mx[4], sm[4], e0[4], e1[4];
#pragma unroll
    for (int r = 0; r < 4; r++) {
      s0[r] = acc[ti][0][r] * scale;
      s1[r] = acc[ti][1][r] * scale;
      float a = v0 ? s0[r] : -1e30f;
      float b = v1 ? s1[r] : -1e30f;
      mx[r] = fmaxf(a, b);
    }
#pragma unroll
    for (int d = 1; d < 16; d <<= 1)
#pragma unroll
      for (int r = 0; r < 4; r++) mx[r] = fmaxf(mx[r], __shfl_xor(mx[r], d));
#pragma unroll
    for (int r = 0; r < 4; r++) {
      e0[r] = v0 ? __expf(s0[r] - mx[r]) : 0.f;
      e1[r] = v1 ? __expf(s1[r] - mx[r]) : 0.f;
      sm[r] = e0[r] + e1[r];
    }
#pragma unroll
    for (int d = 1; d < 16; d <<= 1)
#pragma unroll
      for (int r = 0; r < 4; r++) sm[r] += __shfl_xor(sm[r], d);
#pragma unroll
    for (int r = 0; r < 4; r++) {
      int row = ti * 16 + rowq + r;
      if (row < cnt) {
        float inv = 1.f / sm[r];
        cs0 += e0[r] * inv;
        cs1 += e1[r] * inv;
      }
    }
  }
  cs0 += __shfl_xor(cs0, 16); cs0 += __shfl_xor(cs0, 32);
  cs1 += __shfl_xor(cs1, 16); cs1 += __shfl_xor(cs1, 32);
  if (lane < 16) {
    float invc = 1.f / (float)cnt;
    wsum[h][lane] = cs0 * invc;
    wsum[h][16 + lane] = cs1 * invc;
  }
  __syncthreads();

  // z_h[e] = sum_j wsum[h][j] * emb[j][e]
  for (int e = tid; e < 512; e += 256) {
    float za0 = 0.f, za1 = 0.f, za2 = 0.f, za3 = 0.f;
    for (int j = 0; j < cnt; j++) {
      float ev = byte_emb[((long)tok_s[j] << 9) + e] + local_pos[((long)j << 9) + e];
      za0 += wsum[0][j] * ev;
      za1 += wsum[1][j] * ev;
      za2 += wsum[2][j] * ev;
      za3 += wsum[3][j] * ev;
    }
    long zb = (long)p * 2048;
    Z[zb + e]        = __float2bfloat16(za0);
    Z[zb + 512 + e]  = __float2bfloat16(za1);
    Z[zb + 1024 + e] = __float2bfloat16(za2);
    Z[zb + 1536 + e] = __float2bfloat16(za3);
  }
}

// ---------------------------------------------------------------------------
// Row LayerNorm: fp32 in, fp32 w/b; bf16 out (outb) or fp32 out (outf).
// ---------------------------------------------------------------------------
__global__ __launch_bounds__(256) void ln_kernel(
    const float* __restrict__ x, const float* __restrict__ w, const float* __restrict__ b,
    bf16* outb, float* outf, int N)
{
  __shared__ float red[8];
  __shared__ float mv[2];
  int row = blockIdx.x;
  const float* xr = x + (long)row * N;
  int tid = threadIdx.x, lane = tid & 63, wave = tid >> 6;
  float s = 0.f, s2 = 0.f;
  for (int c = tid; c < N; c += 256) { float v = xr[c]; s += v; s2 += v * v; }
  for (int o = 32; o; o >>= 1) { s += __shfl_down(s, o); s2 += __shfl_down(s2, o); }
  if (lane == 0) { red[wave] = s; red[4 + wave] = s2; }
  __syncthreads();
  if (tid == 0) {
    float ts = red[0] + red[1] + red[2] + red[3];
    float ts2 = red[4] + red[5] + red[6] + red[7];
    float mu = ts / N;
    float var = ts2 / N - mu * mu;
    mv[0] = mu; mv[1] = rsqrtf(var + 1e-5f);
  }
  __syncthreads();
  float mu = mv[0], rstd = mv[1];
  for (int c = tid; c < N; c += 256) {
    float v = (xr[c] - mu) * rstd * w[c] + b[c];
    if (outb) outb[(long)row * N + c] = __float2bfloat16(v);
    if (outf) outf[(long)row * N + c] = v;
  }
}

// ---------------------------------------------------------------------------
// Softmax over 1024 cols, in place on bf16 logits (scale folded in).
// ---------------------------------------------------------------------------
__global__ __launch_bounds__(256) void softmax_bf(u16* __restrict__ S)
{
  __shared__ float red[4], red2[4];
  long row = blockIdx.x;
  u16* sr = S + row * 1024;
  int tid = threadIdx.x, lane = tid & 63, wave = tid >> 6;
  const float scale = 0.10206207261596577f;  // 96^-0.5
  ushort4 raw = *(const ushort4*)(sr + tid * 4);
  float v[4] = {bf2f(raw.x) * scale, bf2f(raw.y) * scale, bf2f(raw.z) * scale, bf2f(raw.w) * scale};
  float m = fmaxf(fmaxf(v[0], v[1]), fmaxf(v[2], v[3]));
  for (int o = 32; o; o >>= 1) m = fmaxf(m, __shfl_down(m, o));
  if (lane == 0) red[wave] = m;
  __syncthreads();
  m = fmaxf(fmaxf(red[0], red[1]), fmaxf(red[2], red[3]));
  float s = 0.f;
#pragma unroll
  for (int k = 0; k < 4; k++) { v[k] = __expf(v[k] - m); s += v[k]; }
  for (int o = 32; o; o >>= 1) s += __shfl_down(s, o);
  if (lane == 0) red2[wave] = s;
  __syncthreads();
  s = red2[0] + red2[1] + red2[2] + red2[3];
  float inv = 1.f / s;
  ushort4 o4;
  o4.x = f2b(v[0] * inv); o4.y = f2b(v[1] * inv); o4.z = f2b(v[2] * inv); o4.w = f2b(v[3] * inv);
  *(ushort4*)(sr + tid * 4) = o4;
}

// ---------------------------------------------------------------------------
// Vt[d][k] = qkv[k][1536 + d]  (V part), 32x32 LDS tiles. bf16.
// ---------------------------------------------------------------------------
__global__ __launch_bounds__(256) void transpose_v(
    const bf16* __restrict__ qkv, bf16* __restrict__ Vt)
{
  __shared__ u16 tile[32][33];
  int k0 = blockIdx.x << 5;
  int d0 = blockIdx.y << 5;
  int tx = threadIdx.x & 31, ty = threadIdx.x >> 5;
  const u16* q = (const u16*)qkv;
  for (int i = ty; i < 32; i += 8)
    tile[i][tx] = q[(long)(k0 + i) * 2304 + 1536 + d0 + tx];
  __syncthreads();
  u16* vt = (u16*)Vt;
  for (int i = ty; i < 32; i += 8)
    vt[(long)(d0 + i) * 1024 + k0 + tx] = tile[tx][i];
}

extern "C" void kernel_launch(void* const* d_in, const int* in_sizes, int n_in,
                              void* d_out, int out_size, void* d_ws, size_t ws_size,
                              hipStream_t stream)
{
  const int*   tokens    = (const int*)d_in[0];
  const int*   lengths   = (const int*)d_in[1];
  const float* byte_emb  = (const float*)d_in[2];
  const float* local_pos = (const float*)d_in[3];
  const float* patch_pos = (const float*)d_in[4];
  const float* pa_qkv_w  = (const float*)d_in[5];
  const float* pa_qkv_b  = (const float*)d_in[6];
  const float* pa_out_w  = (const float*)d_in[7];
  const float* pa_out_b  = (const float*)d_in[8];
  const float* proj_w    = (const float*)d_in[9];
  const float* proj_b    = (const float*)d_in[10];
  const float* Wqkv      = (const float*)d_in[11];
  const float* Bqkv      = (const float*)d_in[12];
  const float* Wout      = (const float*)d_in[13];
  const float* Bout      = (const float*)d_in[14];
  const float* ln1w      = (const float*)d_in[15];
  const float* ln1b      = (const float*)d_in[16];
  const float* ln2w      = (const float*)d_in[17];
  const float* ln2b      = (const float*)d_in[18];
  const float* W1        = (const float*)d_in[19];
  const float* B1        = (const float*)d_in[20];
  const float* W2        = (const float*)d_in[21];
  const float* B2        = (const float*)d_in[22];
  const float* lnfw      = (const float*)d_in[23];
  const float* lnfb      = (const float*)d_in[24];

  char* ws = (char*)d_ws;
  const size_t MB = 1ull << 20;
  // ---- layout (73 MB total; r2-proven budget is >= 82 MB) ----
  bf16* QKC    = (bf16*)(ws);              // [0,64)  phase1 [32768,1024]
  u16*  scores = (u16*)(ws);               // [0,16)  phase2 bf16 [8,1024,1024]
  bf16* qkvt   = (bf16*)(ws + 16 * MB);    // [16,21) [1024,2304]
  bf16* Vt     = (bf16*)(ws + 21 * MB);    // [21,23) [768,1024]
  bf16* attn   = (bf16*)(ws + 23 * MB);    // [23,25) [1024,768]
  bf16* ffb    = (bf16*)(ws + 25 * MB);    // [25,31) [1024,3072]
  float* h     = (float*)(ws + 31 * MB);   // [31,34) [1024,768] fp32
  bf16* hn     = (bf16*)(ws + 34 * MB);    // [34,36)
  u16*  Lw     = (u16*)(ws + 36 * MB);     // [36,50) per-layer bf16 weights
  bf16* Z      = (bf16*)(ws + 64 * MB);    // [64,68) [1024,4,512]
  bf16* o_mean = (bf16*)(ws + 68 * MB);    // [68,69)
  bf16* t1     = (bf16*)(ws + 69 * MB);    // [69,70)
  u16*  P1w    = (u16*)(ws + 70 * MB);     // [70,73) phase1 bf16 weights

  // per-layer pool offsets (u16 elements)
  const long oLQKV = 0;          // [2304,768]
  const long oLOUT = 1769472;    // [768,768]
  const long oLW1  = 2359296;    // [3072,768]
  const long oLW2  = 4718592;    // [768,3072]
  // phase-1 pool offsets
  const long oPAQ  = 0;          // [1536,512]
  const long oPAO  = 786432;     // [512,512]
  const long oPRJ  = 1048576;    // [768,512]

  // ---- phase 1 ----
  cvt4<<<dim3(768, 3), 256, 0, stream>>>(
      pa_qkv_w, pa_out_w, proj_w, nullptr,
      P1w + oPAQ, P1w + oPAO, P1w + oPRJ, nullptr,
      786432 / 4, 262144 / 4, 393216 / 4, 0);
  // QKC = embed(tokens) @ Wqk^T + bqk   [32768,1024], embed fused in A-staging
  gemm64<true><<<dim3(512, 16, 1), 256, 0, stream>>>(
      nullptr, 0, 0, (bf16*)(P1w + oPAQ), 0, EE, nullptr, QKC, 0, 1024,
      pa_qkv_b, 0, nullptr, 32768, 1024, EE, 0,
      tokens, lengths, byte_emb, local_pos);
  patch_attn<<<PP, 256, 0, stream>>>(
      QKC, tokens, lengths, byte_emb, local_pos, Z);
  // o_mean[:, h*128:(h+1)*128] = Z[:,h,:] @ Wv_h^T + bv_h
  gemm64<false><<<dim3(16, 2, 4), 256, 0, stream>>>(
      Z, 512, 2048, (bf16*)(P1w + oPAQ + 1024L * EE), 128L * EE, EE,
      nullptr, o_mean, 128, EE, pa_qkv_b + 1024, 128, nullptr, PP, 128, EE, 0,
      nullptr, nullptr, nullptr, nullptr);
  // t1 = o_mean @ pa_out_w^T + b
  gemm64<false><<<dim3(16, 8, 1), 256, 0, stream>>>(
      o_mean, 0, EE, (bf16*)(P1w + oPAO), 0, EE, nullptr, t1, 0, EE,
      pa_out_b, 0, nullptr, PP, EE, EE, 0,
      nullptr, nullptr, nullptr, nullptr);
  // h = t1 @ proj_w^T + b + patch_pos (fp32)
  gemm64<false><<<dim3(16, 12, 1), 256, 0, stream>>>(
      t1, 0, EE, (bf16*)(P1w + oPRJ), 0, EE, h, nullptr, 0, DD,
      proj_b, 0, patch_pos, PP, DD, EE, 0,
      nullptr, nullptr, nullptr, nullptr);

  // ---- phase 2: transformer encoder ----
  for (int i = 0; i < NLAYER; i++) {
    cvt4<<<dim3(2304, 4), 256, 0, stream>>>(
        Wqkv + (long)i * 2304 * DD, Wout + (long)i * DD * DD,
        W1 + (long)i * FFDIM * DD, W2 + (long)i * DD * FFDIM,
        Lw + oLQKV, Lw + oLOUT, Lw + oLW1, Lw + oLW2,
        1769472 / 4, 589824 / 4, 2359296 / 4, 2359296 / 4);
    ln_kernel<<<PP, 256, 0, stream>>>(h, ln1w + i * DD, ln1b + i * DD, hn, nullptr, DD);
    gemm64<false><<<dim3(16, 36, 1), 256, 0, stream>>>(
        hn, 0, DD, (bf16*)(Lw + oLQKV), 0, DD, nullptr, qkvt, 0, 2304,
        Bqkv + i * 2304, 0, nullptr, PP, 2304, DD, 0,
        nullptr, nullptr, nullptr, nullptr);
    // scores[h] = Q_h @ K_h^T (bf16 logits)
    gemm64<false><<<dim3(16, 16, 8), 256, 0, stream>>>(
        qkvt, 96, 2304, qkvt + DD, 96, 2304, nullptr, (bf16*)scores, 1024L * 1024, 1024,
        nullptr, 0, nullptr, 1024, 1024, 96, 0,
        nullptr, nullptr, nullptr, nullptr);
    softmax_bf<<<8192, 256, 0, stream>>>(scores);
    transpose_v<<<dim3(32, 24), 256, 0, stream>>>(qkvt, Vt);
    // attn[:, h*96:(h+1)*96] = P_h @ V_h
    gemm64<false><<<dim3(16, 2, 8), 256, 0, stream>>>(
        (bf16*)scores, 1024L * 1024, 1024, Vt, 96L * 1024, 1024, nullptr, attn, 96, DD,
        nullptr, 0, nullptr, 1024, 96, 1024, 0,
        nullptr, nullptr, nullptr, nullptr);
    // h += attn @ Wout^T + bo
    gemm64<false><<<dim3(16, 12, 1), 256, 0, stream>>>(
        attn, 0, DD, (bf16*)(Lw + oLOUT), 0, DD, h, nullptr, 0, DD,
        Bout + i * DD, 0, h, PP, DD, DD, 0,
        nullptr, nullptr, nullptr, nullptr);
    ln_kernel<<<PP, 256, 0, stream>>>(h, ln2w + i * DD, ln2b + i * DD, hn, nullptr, DD);
    // ffb = gelu(hn @ W1^T + b1)
    gemm64<false><<<dim3(16, 48, 1), 256, 0, stream>>>(
        hn, 0, DD, (bf16*)(Lw + oLW1), 0, DD, nullptr, ffb, 0, FFDIM,
        B1 + i * FFDIM, 0, nullptr, PP, FFDIM, DD, 1,
        nullptr, nullptr, nullptr, nullptr);
    // h += ffb @ W2^T + b2
    gemm64<false><<<dim3(16, 12, 1), 256, 0, stream>>>(
        ffb, 0, FFDIM, (bf16*)(Lw + oLW2), 0, FFDIM, h, nullptr, 0, DD,
        B2 + i * DD, 0, h, PP, DD, FFDIM, 0,
        nullptr, nullptr, nullptr, nullptr);
  }
  ln_kernel<<<PP, 256, 0, stream>>>(h, lnfw, lnfb, nullptr, (float*)d_out, DD);
}